// Round 1
// baseline (302.615 us; speedup 1.0000x reference)
//
#include <hip/hip_runtime.h>

#define NB 4
#define N_NODES 100000
#define E_EDGES 160000
#define EA 80000
#define HID 128
#define ED 16

#define TILE_M 64
#define THREADS 256

__global__ __launch_bounds__(THREADS, 2) void actor_head_kernel(
    const float* __restrict__ h,          // [B][N][128]
    const int*   __restrict__ edge_index, // [2][E]
    const float* __restrict__ edge_attr,  // [B][E][16]
    const int*   __restrict__ etype,      // [EA]
    const float* __restrict__ W1,         // [272][128]
    const float* __restrict__ b1,         // [128]
    const float* __restrict__ W2,         // [128][2]
    const float* __restrict__ b2,         // [2]
    float*       __restrict__ out)        // [B][EA/2][2]
{
    __shared__ float xs[64][68];     // [kk][m], pad 68 keeps 16B row alignment
    __shared__ float ws[64][132];    // [kk][n]
    __shared__ int sel_r[TILE_M], sel_s[TILE_M], sel_e[TILE_M];

    const int b  = blockIdx.y;
    const int e0 = blockIdx.x * TILE_M;
    const int t  = threadIdx.x;

    if (t < TILE_M) {
        int ei = etype[e0 + t];
        sel_e[t] = ei;
        sel_r[t] = edge_index[ei];
        sel_s[t] = edge_index[E_EDGES + ei];
    }

    const int tm = t >> 5;        // 0..7  -> rows m0..m0+7
    const int tn = t & 31;        // 0..31 -> cols n0..n0+3
    const int m0 = tm * 8;
    const int n0 = tn * 4;

    // staging roles
    const int sm = t >> 2;        // 0..63 : which edge row I help stage
    const int sq = t & 3;         // 0..3  : which 16-float piece of that row
    const int krow = t >> 5;      // 0..7  : W1 staging row phase

    float acc[8][4];
    #pragma unroll
    for (int i = 0; i < 8; ++i)
        #pragma unroll
        for (int j = 0; j < 4; ++j) acc[i][j] = 0.f;

    __syncthreads();

    // ---- 4 main K-chunks of 64 (c=0,1 from h[sel_r], c=2,3 from h[sel_s]) ----
    for (int c = 0; c < 4; ++c) {
        const int kbase = (c & 1) * 64;
        const int* sel = (c < 2) ? sel_r : sel_s;

        // stage x-tile transposed: row sm, k = kbase + sq*16 + {0..15}
        {
            const float* src = h + ((size_t)b * N_NODES + sel[sm]) * HID + kbase + sq * 16;
            #pragma unroll
            for (int j = 0; j < 4; ++j) {
                float4 v = *reinterpret_cast<const float4*>(src + j * 4);
                int kk = sq * 16 + j * 4;
                xs[kk + 0][sm] = v.x;
                xs[kk + 1][sm] = v.y;
                xs[kk + 2][sm] = v.z;
                xs[kk + 3][sm] = v.w;
            }
        }
        // stage W1 chunk: rows kglob = c*64 + kk
        {
            #pragma unroll
            for (int j = 0; j < 8; ++j) {
                int kk = j * 8 + krow;
                float4 v = *reinterpret_cast<const float4*>(
                    W1 + (size_t)(c * 64 + kk) * HID + tn * 4);
                *reinterpret_cast<float4*>(&ws[kk][tn * 4]) = v;
            }
        }
        __syncthreads();

        #pragma unroll 8
        for (int kk = 0; kk < 64; ++kk) {
            float4 xa = *reinterpret_cast<const float4*>(&xs[kk][m0]);
            float4 xb = *reinterpret_cast<const float4*>(&xs[kk][m0 + 4]);
            float4 wv = *reinterpret_cast<const float4*>(&ws[kk][n0]);
            float xv[8] = {xa.x, xa.y, xa.z, xa.w, xb.x, xb.y, xb.z, xb.w};
            float wvv[4] = {wv.x, wv.y, wv.z, wv.w};
            #pragma unroll
            for (int i = 0; i < 8; ++i)
                #pragma unroll
                for (int j = 0; j < 4; ++j)
                    acc[i][j] = fmaf(xv[i], wvv[j], acc[i][j]);
        }
        __syncthreads();
    }

    // ---- tail K-chunk of 16 from edge_attr ----
    {
        // x: 64 rows x 16 floats; thread t: row sm, floats sq*4..sq*4+3
        float4 v = *reinterpret_cast<const float4*>(
            edge_attr + ((size_t)b * E_EDGES + sel_e[sm]) * ED + sq * 4);
        int kk = sq * 4;
        xs[kk + 0][sm] = v.x;
        xs[kk + 1][sm] = v.y;
        xs[kk + 2][sm] = v.z;
        xs[kk + 3][sm] = v.w;

        // W1 rows 256..271
        #pragma unroll
        for (int j = 0; j < 2; ++j) {
            int kk2 = j * 8 + krow;   // 0..15
            float4 w = *reinterpret_cast<const float4*>(
                W1 + (size_t)(256 + kk2) * HID + tn * 4);
            *reinterpret_cast<float4*>(&ws[kk2][tn * 4]) = w;
        }
        __syncthreads();

        #pragma unroll
        for (int kk3 = 0; kk3 < 16; ++kk3) {
            float4 xa = *reinterpret_cast<const float4*>(&xs[kk3][m0]);
            float4 xb = *reinterpret_cast<const float4*>(&xs[kk3][m0 + 4]);
            float4 wv = *reinterpret_cast<const float4*>(&ws[kk3][n0]);
            float xv[8] = {xa.x, xa.y, xa.z, xa.w, xb.x, xb.y, xb.z, xb.w};
            float wvv[4] = {wv.x, wv.y, wv.z, wv.w};
            #pragma unroll
            for (int i = 0; i < 8; ++i)
                #pragma unroll
                for (int j = 0; j < 4; ++j)
                    acc[i][j] = fmaf(xv[i], wvv[j], acc[i][j]);
        }
    }

    // ---- epilogue: y = relu(acc + b1); o = y @ W2; pair-mean; + b2 ----
    float b1a[4], w2a[4], w2b[4];
    #pragma unroll
    for (int j = 0; j < 4; ++j) {
        b1a[j] = b1[n0 + j];
        w2a[j] = W2[(n0 + j) * 2 + 0];
        w2b[j] = W2[(n0 + j) * 2 + 1];
    }
    const float b20 = b2[0], b21 = b2[1];

    float o0[8], o1[8];
    #pragma unroll
    for (int i = 0; i < 8; ++i) {
        float p0 = 0.f, p1 = 0.f;
        #pragma unroll
        for (int j = 0; j < 4; ++j) {
            float y = fmaxf(acc[i][j] + b1a[j], 0.f);
            p0 = fmaf(y, w2a[j], p0);
            p1 = fmaf(y, w2b[j], p1);
        }
        // reduce across the 32 lanes sharing these rows
        #pragma unroll
        for (int off = 16; off >= 1; off >>= 1) {
            p0 += __shfl_xor(p0, off, 32);
            p1 += __shfl_xor(p1, off, 32);
        }
        o0[i] = p0;
        o1[i] = p1;
    }

    if (tn == 0) {
        #pragma unroll
        for (int i = 0; i < 8; i += 2) {
            int r = e0 + m0 + i;              // even edge row within EA
            size_t oi = ((size_t)b * (EA / 2) + (r >> 1)) * 2;
            out[oi + 0] = 0.5f * (o0[i] + o0[i + 1]) + b20;
            out[oi + 1] = 0.5f * (o1[i] + o1[i + 1]) + b21;
        }
    }
}

extern "C" void kernel_launch(void* const* d_in, const int* in_sizes, int n_in,
                              void* d_out, int out_size, void* d_ws, size_t ws_size,
                              hipStream_t stream) {
    const float* h          = (const float*)d_in[0];
    const int*   edge_index = (const int*)d_in[1];
    const float* edge_attr  = (const float*)d_in[2];
    const int*   etype      = (const int*)d_in[3];
    const float* W1         = (const float*)d_in[4];
    const float* b1         = (const float*)d_in[5];
    const float* W2         = (const float*)d_in[6];
    const float* b2         = (const float*)d_in[7];
    float* out = (float*)d_out;

    dim3 grid(EA / TILE_M, NB);
    actor_head_kernel<<<grid, THREADS, 0, stream>>>(
        h, edge_index, edge_attr, etype, W1, b1, W2, b2, out);
}

// Round 3
// 67.831 us; speedup vs baseline: 4.4613x; 4.4613x over previous
//
#include <hip/hip_runtime.h>

#define NB 4
#define N_NODES 100000
#define E_EDGES 160000
#define EA_E 80000
#define HID 128
#define ED 16

#define TILE_M 128
#define THREADS 256
#define XPAD 40   // row length in ushort (32 used) -> 80B stride; reads 2-way-free
#define WPAD 40

typedef __attribute__((ext_vector_type(8))) short bf16x8;
typedef __attribute__((ext_vector_type(4))) float f32x4;
typedef __attribute__((ext_vector_type(8))) unsigned short u16x8;
typedef __attribute__((ext_vector_type(4))) unsigned short u16x4;

__device__ __forceinline__ unsigned short f2bf(float f) {
    union { float f; unsigned u; } v; v.f = f;
    return (unsigned short)((v.u + 0x7fffu + ((v.u >> 16) & 1u)) >> 16);
}

__global__ __launch_bounds__(THREADS, 3) void actor_head_mfma(
    const float* __restrict__ h,          // [B][N][128]
    const int*   __restrict__ edge_index, // [2][E]
    const float* __restrict__ edge_attr,  // [B][E][16]
    const int*   __restrict__ etype,      // [EA]
    const float* __restrict__ W1,         // [272][128]
    const float* __restrict__ b1,         // [128]
    const float* __restrict__ W2,         // [128][2]
    const float* __restrict__ b2,         // [2]
    float*       __restrict__ out)        // [B][EA/2][2]
{
    __shared__ unsigned short xs[TILE_M][XPAD];  // x tile, [m][k_local]
    __shared__ unsigned short ws[HID][WPAD];     // W1 tile transposed, [n][k_local]
    __shared__ int sel[3][TILE_M];               // 0: recv, 1: sent, 2: edge

    const int b  = blockIdx.y;
    const int e0 = blockIdx.x * TILE_M;
    const int t  = threadIdx.x;

    if (t < TILE_M) {
        int ei = etype[e0 + t];
        sel[2][t] = ei;
        sel[0][t] = edge_index[ei];
        sel[1][t] = edge_index[E_EDGES + ei];
    }

    const int lane = t & 63;
    const int wid  = t >> 6;          // 0..3
    const int wm   = wid * 32;        // wave owns rows wm..wm+31, ALL 128 cols
    const int fr   = lane & 15;       // fragment row/col index
    const int fq   = lane >> 4;       // fragment k-group / reg-group

    // staging roles
    const int sm = t >> 1;            // x row 0..127
    const int sh = t & 1;             // which 16-float half of the 32-k chunk
    const int kb = t >> 5;            // W1 k sub-block 0..7 (4 k each)
    const int nb = t & 31;            // W1 n sub-block (4 n each)

    f32x4 acc[2][8];
    #pragma unroll
    for (int i = 0; i < 2; ++i)
        #pragma unroll
        for (int j = 0; j < 8; ++j) acc[i][j] = (f32x4){0.f, 0.f, 0.f, 0.f};

    __syncthreads();

    for (int c = 0; c < 9; ++c) {
        // ---------- stage x tile: rows = gathered edges, 32 k per step ----------
        {
            unsigned short tmp[16];
            if (c < 8) {
                const int node = (c < 4) ? sel[0][sm] : sel[1][sm];
                const float* src = h + ((size_t)b * N_NODES + node) * HID
                                     + (c & 3) * 32 + sh * 16;
                #pragma unroll
                for (int j = 0; j < 4; ++j) {
                    f32x4 v = *reinterpret_cast<const f32x4*>(src + j * 4);
                    tmp[j * 4 + 0] = f2bf(v[0]);
                    tmp[j * 4 + 1] = f2bf(v[1]);
                    tmp[j * 4 + 2] = f2bf(v[2]);
                    tmp[j * 4 + 3] = f2bf(v[3]);
                }
            } else if (sh == 0) {
                const float* src = edge_attr + ((size_t)b * E_EDGES + sel[2][sm]) * ED;
                #pragma unroll
                for (int j = 0; j < 4; ++j) {
                    f32x4 v = *reinterpret_cast<const f32x4*>(src + j * 4);
                    tmp[j * 4 + 0] = f2bf(v[0]);
                    tmp[j * 4 + 1] = f2bf(v[1]);
                    tmp[j * 4 + 2] = f2bf(v[2]);
                    tmp[j * 4 + 3] = f2bf(v[3]);
                }
            } else {
                #pragma unroll
                for (int j = 0; j < 16; ++j) tmp[j] = 0;
            }
            u16x8 lo, hi;
            #pragma unroll
            for (int j = 0; j < 8; ++j) { lo[j] = tmp[j]; hi[j] = tmp[8 + j]; }
            *reinterpret_cast<u16x8*>(&xs[sm][sh * 16 + 0]) = lo;
            *reinterpret_cast<u16x8*>(&xs[sm][sh * 16 + 8]) = hi;
        }

        // ---------- stage W1 chunk transposed: ws[n][k_local] ----------
        {
            const int k0 = kb * 4;
            const int n0 = nb * 4;
            float vals[4][4]; // [k][n]
            const bool valid = (c < 8) || (k0 < 16); // step 8: k_local 16..31 are pad
            if (valid) {
                #pragma unroll
                for (int i = 0; i < 4; ++i) {
                    f32x4 v = *reinterpret_cast<const f32x4*>(
                        W1 + (size_t)(c * 32 + k0 + i) * HID + n0);
                    vals[i][0] = v[0]; vals[i][1] = v[1];
                    vals[i][2] = v[2]; vals[i][3] = v[3];
                }
            } else {
                #pragma unroll
                for (int i = 0; i < 4; ++i)
                    #pragma unroll
                    for (int j = 0; j < 4; ++j) vals[i][j] = 0.f;
            }
            #pragma unroll
            for (int j = 0; j < 4; ++j) {
                u16x4 w;
                w[0] = f2bf(vals[0][j]); w[1] = f2bf(vals[1][j]);
                w[2] = f2bf(vals[2][j]); w[3] = f2bf(vals[3][j]);
                *reinterpret_cast<u16x4*>(&ws[n0 + j][k0]) = w;
            }
        }
        __syncthreads();

        // ---------- MFMA: wave computes 32 rows x 128 cols via 2x8 fragments ----------
        {
            bf16x8 af[2], bw[8];
            #pragma unroll
            for (int mi = 0; mi < 2; ++mi)
                af[mi] = *reinterpret_cast<const bf16x8*>(&xs[wm + mi * 16 + fr][fq * 8]);
            #pragma unroll
            for (int ni = 0; ni < 8; ++ni)
                bw[ni] = *reinterpret_cast<const bf16x8*>(&ws[ni * 16 + fr][fq * 8]);
            #pragma unroll
            for (int mi = 0; mi < 2; ++mi)
                #pragma unroll
                for (int ni = 0; ni < 8; ++ni)
                    acc[mi][ni] = __builtin_amdgcn_mfma_f32_16x16x32_bf16(
                        af[mi], bw[ni], acc[mi][ni], 0, 0, 0);
        }
        __syncthreads();
    }

    // ---------- epilogue: relu(+b1), @W2, pair-mean, +b2 ----------
    float b1v[8], w2a[8], w2b[8];
    #pragma unroll
    for (int ni = 0; ni < 8; ++ni) {
        int n = ni * 16 + fr;
        b1v[ni] = b1[n];
        w2a[ni] = W2[2 * n + 0];
        w2b[ni] = W2[2 * n + 1];
    }
    const float b20 = b2[0], b21 = b2[1];

    #pragma unroll
    for (int mi = 0; mi < 2; ++mi) {
        #pragma unroll
        for (int j = 0; j < 2; ++j) {
            // rows fq*4 + 2j (even) and fq*4 + 2j+1 (odd) form one output pair
            float s0 = 0.f, s1 = 0.f;
            #pragma unroll
            for (int ni = 0; ni < 8; ++ni) {
                float y0 = fmaxf(acc[mi][ni][2 * j]     + b1v[ni], 0.f);
                float y1 = fmaxf(acc[mi][ni][2 * j + 1] + b1v[ni], 0.f);
                float ys = y0 + y1;
                s0 = fmaf(ys, w2a[ni], s0);
                s1 = fmaf(ys, w2b[ni], s1);
            }
            #pragma unroll
            for (int off = 8; off >= 1; off >>= 1) {
                s0 += __shfl_xor(s0, off);
                s1 += __shfl_xor(s1, off);
            }
            if (fr == 0) {
                int mg = e0 + wm + mi * 16 + fq * 4 + 2 * j; // even edge row
                size_t oi = ((size_t)b * (EA_E / 2) + (mg >> 1)) * 2;
                out[oi + 0] = 0.5f * s0 + b20;
                out[oi + 1] = 0.5f * s1 + b21;
            }
        }
    }
}

extern "C" void kernel_launch(void* const* d_in, const int* in_sizes, int n_in,
                              void* d_out, int out_size, void* d_ws, size_t ws_size,
                              hipStream_t stream) {
    const float* h          = (const float*)d_in[0];
    const int*   edge_index = (const int*)d_in[1];
    const float* edge_attr  = (const float*)d_in[2];
    const int*   etype      = (const int*)d_in[3];
    const float* W1         = (const float*)d_in[4];
    const float* b1         = (const float*)d_in[5];
    const float* W2         = (const float*)d_in[6];
    const float* b2         = (const float*)d_in[7];
    float* out = (float*)d_out;

    dim3 grid(EA_E / TILE_M, NB);
    actor_head_mfma<<<grid, THREADS, 0, stream>>>(
        h, edge_index, edge_attr, etype, W1, b1, W2, b2, out);
}